// Round 6
// baseline (6553.122 us; speedup 1.0000x reference)
//
#include <hip/hip_runtime.h>
#include <hip/hip_bf16.h>
#include <math.h>

// ---------------------------------------------------------------------------
// Round 6: persistent kernel; fragment-linear LDS weights (0 bank conflicts);
// h-loads via L2 (plain loads) with 64-slot rings + periodic agent acquire
// fence (buffer_inv) closing the stale-line window; h-stores stay sc0sc1
// write-through (round-5-proven). Geometry/numerics identical to round 5:
// [0,64) L0 16-col blocks, [64,192) L1 8-col, [192,196) FC.
// ws: weights 26.5MB + 2 rings 17MB + flags = ~43.5MB
// ---------------------------------------------------------------------------

#define S_LEN 512
#define B_SZ  64
#define V_SZ  128
#define H_SZ  1024
#define BH    65536
#define RING  64
#define SLOT  66560          // BH + 1024 u16 pad (prefetch guard)
#define FSTR  16             // ints per flag slot
#define INVP  48             // acquire-fence period (must be < RING-8)

typedef unsigned short u16;
typedef unsigned short u16x8 __attribute__((ext_vector_type(8)));
typedef __bf16         bf16x8 __attribute__((ext_vector_type(8)));
typedef float          f32x4  __attribute__((ext_vector_type(4)));
typedef int            i32x4  __attribute__((ext_vector_type(4)));

__device__ __forceinline__ u16 f2bf(float f) {
    unsigned int u = __float_as_uint(f);
    u += 0x7fffu + ((u >> 16) & 1u);
    return (u16)(u >> 16);
}
__device__ __forceinline__ f32x4 mfma16(u16x8 a, u16x8 b, f32x4 c) {
    return __builtin_amdgcn_mfma_f32_16x16x32_bf16(
        __builtin_bit_cast(bf16x8, a), __builtin_bit_cast(bf16x8, b), c, 0, 0, 0);
}
__device__ __forceinline__ f32x4 mfma16(i32x4 a, u16x8 b, f32x4 c) {
    return __builtin_amdgcn_mfma_f32_16x16x32_bf16(
        __builtin_bit_cast(bf16x8, a), __builtin_bit_cast(bf16x8, b), c, 0, 0, 0);
}

// plain cached load (L1/L2 path) into explicit VGPRs for the counted pipeline
__device__ __forceinline__ void ld_g(i32x4& d, const u16* p) {
    asm volatile("global_load_dwordx4 %0, %1, off" : "=v"(d) : "v"(p));
}
// coherent (write-through to coherence point) h store — round-5-proven
__device__ __forceinline__ void st_coh_u16(u16* p, u16 v) {
    unsigned int vv = v;
    asm volatile("global_store_short %0, %1, off sc0 sc1" :: "v"(p), "v"(vv));
}
__device__ __forceinline__ int ld_flag(const int* p) {
    int v;
    asm volatile("global_load_dword %0, %1, off sc0 sc1\n\ts_waitcnt vmcnt(0)"
                 : "=v"(v) : "v"(p) : "memory");
    return v;
}
__device__ __forceinline__ void st_flag(int* p, int v) {
    asm volatile("global_store_dword %0, %1, off sc0 sc1" :: "v"(p), "v"(v));
}
#define WAITV(n) asm volatile("s_waitcnt vmcnt(" #n ")" ::: "memory")
#define SCHEDB   __builtin_amdgcn_sched_barrier(0)

__device__ __forceinline__ void l2_acquire_inv() {
    // emits s_waitcnt + buffer_inv (L1+L2 invalidate, dirty lines preserved)
    __builtin_amdgcn_fence(__ATOMIC_ACQUIRE, "agent");
}

__global__ __launch_bounds__(256) void cvt_kernel(const float* __restrict__ s,
                                                  u16* __restrict__ d, int n)
{
    int i = (blockIdx.x * 256 + threadIdx.x) * 4;
    if (i >= n) return;
    float4 v = *(const float4*)(s + i);
    ushort4 o;
    o.x = f2bf(v.x); o.y = f2bf(v.y); o.z = f2bf(v.z); o.w = f2bf(v.w);
    *(ushort4*)(d + i) = o;
}

// fragment-linear LDS: frag (idx) at [(idx*64 + lane)*8] u16; a wave's read of
// one frag covers 1024 contiguous bytes -> zero bank conflicts.
union SMemL {
    struct { u16 wih[4 * 4 * 64 * 8]; u16 whh[32 * 4 * 64 * 8]; } l0;  // 16KB+128KB
    struct { u16 w[2 * 32 * 2 * 64 * 8]; } l1;                         // 128KB
    float lg[16][132];
};

__global__ __launch_bounds__(256, 1) void persist_kernel(
    const float* __restrict__ x,
    const u16* __restrict__ Wih0c, const u16* __restrict__ Whh0c,
    const u16* __restrict__ Wih1c, const u16* __restrict__ Whh1c,
    const u16* __restrict__ Wfcc,
    const float* __restrict__ bih0, const float* __restrict__ bhh0,
    const float* __restrict__ bih1, const float* __restrict__ bhh1,
    const float* __restrict__ bfc,
    u16* __restrict__ h0b, u16* __restrict__ h1b,
    int* __restrict__ flagL0, int* __restrict__ flagL1, int* __restrict__ flagFC,
    float* __restrict__ out)
{
    __shared__ SMemL sm;
    const int bid = blockIdx.x, tid = threadIdx.x;
    const int wave = tid >> 6, lane = tid & 63;
    const int l16 = lane & 15, kgi = lane >> 4, kg8 = kgi * 8;

    // ======================= LAYER 0 : blocks 0..63 =======================
    if (bid < 64) {
        const int j0 = bid * 16, jj = j0 + l16;
        // stage Wih0 slice: 1024 frags, row-order rl = g*16 + jloc
        #pragma unroll
        for (int i = 0; i < 4; ++i) {
            int f = tid + i * 256;
            int rl = f >> 4, kf = f & 15;
            int c = kf >> 2, kg = kf & 3;
            int g = rl >> 4, jl = rl & 15;
            int gr = g * H_SZ + j0 + jl;
            *(u16x8*)&sm.l0.wih[(((c * 4 + g) * 64) + kg * 16 + jl) * 8] =
                *(const u16x8*)(Wih0c + (size_t)gr * V_SZ + kf * 8);
        }
        // stage Whh0 slice: 8192 frags
        #pragma unroll
        for (int i = 0; i < 32; ++i) {
            int f = tid + i * 256;
            int rl = f >> 7, kf = f & 127;
            int c = kf >> 2, kg = kf & 3;
            int g = rl >> 4, jl = rl & 15;
            int gr = g * H_SZ + j0 + jl;
            *(u16x8*)&sm.l0.whh[(((c * 4 + g) * 64) + kg * 16 + jl) * 8] =
                *(const u16x8*)(Whh0c + (size_t)gr * H_SZ + kf * 8);
        }
        __syncthreads();

        const float bii = bih0[jj]            + bhh0[jj];
        const float bif = bih0[H_SZ + jj]     + bhh0[H_SZ + jj];
        const float big = bih0[2 * H_SZ + jj] + bhh0[2 * H_SZ + jj];
        const float bio = bih0[3 * H_SZ + jj] + bhh0[3 * H_SZ + jj];

        const int arow = wave * 16 + l16;
        const float* xrow = x + (size_t)arow * (S_LEN * V_SZ);
        float creg[4] = {0.f, 0.f, 0.f, 0.f};

        for (int t = 0; t < S_LEN; ++t) {
            // waits: h0[t-1] complete (all 64 L0); WAR: L1 done t-64 before slot reuse
            {
                const int* p = nullptr; int tgt = 0;
                if (tid < 64)                        { p = flagL0 + tid * FSTR;        tgt = t; }
                else if (tid < 192 && t >= RING)     { p = flagL1 + (tid - 64) * FSTR; tgt = t - (RING - 1); }
                if (p && tgt > 0) while (ld_flag(p) < tgt) __builtin_amdgcn_s_sleep(2);
                __syncthreads();
            }
            if (t >= INVP && (t % INVP) == 0) l2_acquire_inv();

            f32x4 acc[4][2] = {};
            // pass 1: x_t (cached loads, fp32 -> bf16)
            {
                const float* xp = xrow + (size_t)t * V_SZ + kg8;
                #pragma unroll
                for (int i = 0; i < 4; ++i) {
                    float4 u = *(const float4*)(xp + i * 32);
                    float4 v = *(const float4*)(xp + i * 32 + 4);
                    u16x8 af;
                    af[0] = f2bf(u.x); af[1] = f2bf(u.y); af[2] = f2bf(u.z); af[3] = f2bf(u.w);
                    af[4] = f2bf(v.x); af[5] = f2bf(v.y); af[6] = f2bf(v.z); af[7] = f2bf(v.w);
                    #pragma unroll
                    for (int g = 0; g < 4; ++g)
                        acc[g][i & 1] = mfma16(af,
                            *(const u16x8*)&sm.l0.wih[((i * 4 + g) * 64 + lane) * 8], acc[g][i & 1]);
                }
            }
            // pass 2: h0[t-1] (L2-cached counted pipeline)
            {
                auto ISSUE = [&](i32x4 (&buf)[8], const u16* base) {
                    #pragma unroll
                    for (int q = 0; q < 8; ++q) ld_g(buf[q], base + q * 32);
                };
                auto COMP = [&](i32x4 (&buf)[8], int k0) {
                    #pragma unroll
                    for (int q = 0; q < 8; ++q) {
                        #pragma unroll
                        for (int g = 0; g < 4; ++g)
                            acc[g][q & 1] = mfma16(buf[q],
                                *(const u16x8*)&sm.l0.whh[(((k0 + q) * 4 + g) * 64 + lane) * 8],
                                acc[g][q & 1]);
                    }
                };
                const u16* aB = h0b + (size_t)((t - 1) & (RING - 1)) * SLOT
                              + (size_t)arow * H_SZ + kg8;
                i32x4 b0[8], b1[8];
                WAITV(0);
                ISSUE(b0, aB);
                ISSUE(b1, aB + 256); WAITV(8); SCHEDB; COMP(b0, 0);
                ISSUE(b0, aB + 512); WAITV(8); SCHEDB; COMP(b1, 8);
                ISSUE(b1, aB + 768); WAITV(8); SCHEDB; COMP(b0, 16);
                                     WAITV(0); SCHEDB; COMP(b1, 24);
            }
            // fused LSTM update + coherent h store
            {
                u16* hout = h0b + (size_t)(t & (RING - 1)) * SLOT;
                #pragma unroll
                for (int r = 0; r < 4; ++r) {
                    const int m = wave * 16 + kgi * 4 + r;
                    const float ip = acc[0][0][r] + acc[0][1][r] + bii;
                    const float fp = acc[1][0][r] + acc[1][1][r] + bif;
                    const float gp = acc[2][0][r] + acc[2][1][r] + big;
                    const float op = acc[3][0][r] + acc[3][1][r] + bio;
                    const float iv = 1.f / (1.f + expf(-ip));
                    const float fv = 1.f / (1.f + expf(-fp));
                    const float gv = tanhf(gp);
                    const float ov = 1.f / (1.f + expf(-op));
                    const float cv = fv * creg[r] + iv * gv;
                    creg[r] = cv;
                    st_coh_u16(hout + (size_t)m * H_SZ + jj, f2bf(ov * tanhf(cv)));
                }
                WAITV(0);
            }
            __syncthreads();
            if (tid == 0) st_flag(flagL0 + bid * FSTR, t + 1);
        }
        return;
    }

    // ======================= LAYER 1 : blocks 64..191 =======================
    if (bid < 192) {
        const int lb = bid - 64, j0 = lb * 8, jj2 = j0 + (l16 & 7);
        // stage Wih1+Whh1 slices: 8192 frags, row-order rl = g*8 + jloc (32 rows/region)
        #pragma unroll
        for (int i = 0; i < 32; ++i) {
            int f = tid + i * 256;
            int region = f >> 12;
            int r2 = f & 4095;
            int rl = r2 >> 7, kf = r2 & 127;
            int c = kf >> 2, kg = kf & 3;
            int nt = rl >> 4, jl = rl & 15;
            int gr = (rl >> 3) * H_SZ + j0 + (rl & 7);
            const u16* src = (region ? Whh1c : Wih1c) + (size_t)gr * H_SZ + kf * 8;
            *(u16x8*)&sm.l1.w[((((region * 32 + c) * 2 + nt) * 64) + kg * 16 + jl) * 8] =
                *(const u16x8*)src;
        }
        __syncthreads();

        const float bii = bih1[jj2]            + bhh1[jj2];
        const float bif = bih1[H_SZ + jj2]     + bhh1[H_SZ + jj2];
        const float big = bih1[2 * H_SZ + jj2] + bhh1[2 * H_SZ + jj2];
        const float bio = bih1[3 * H_SZ + jj2] + bhh1[3 * H_SZ + jj2];
        const bool lo = (l16 < 8);

        const int arow = wave * 16 + l16;
        float creg[4] = {0.f, 0.f, 0.f, 0.f};

        for (int t = 0; t < S_LEN; ++t) {
            {
                const int* p = nullptr; int tgt = 0;
                if (tid < 64)                        { p = flagL0 + tid * FSTR;         tgt = t + 1; }
                else if (tid < 192)                  { p = flagL1 + (tid - 64) * FSTR;  tgt = t; }
                else if (tid < 196 && t >= RING)     { p = flagFC + (tid - 192) * FSTR; tgt = t - (RING - 1); }
                if (p && tgt > 0) while (ld_flag(p) < tgt) __builtin_amdgcn_s_sleep(2);
                __syncthreads();
            }
            if (t >= INVP && (t % INVP) == 0) l2_acquire_inv();

            f32x4 acc[2][2] = {};
            {
                auto ISSUE = [&](i32x4 (&buf)[8], const u16* base) {
                    #pragma unroll
                    for (int q = 0; q < 8; ++q) ld_g(buf[q], base + q * 32);
                };
                auto COMP = [&](i32x4 (&buf)[8], int region, int c0) {
                    #pragma unroll
                    for (int q = 0; q < 8; ++q) {
                        #pragma unroll
                        for (int nt = 0; nt < 2; ++nt)
                            acc[nt][q & 1] = mfma16(buf[q],
                                *(const u16x8*)&sm.l1.w[(((region * 32 + c0 + q) * 2 + nt) * 64 + lane) * 8],
                                acc[nt][q & 1]);
                    }
                };
                const u16* a1 = h0b + (size_t)(t & (RING - 1)) * SLOT
                              + (size_t)arow * H_SZ + kg8;                     // h0[t]
                const u16* a2 = h1b + (size_t)((t - 1) & (RING - 1)) * SLOT
                              + (size_t)arow * H_SZ + kg8;                     // h1[t-1]
                i32x4 b0[8], b1[8];
                WAITV(0);
                ISSUE(b0, a1);
                ISSUE(b1, a1 + 256); WAITV(8); SCHEDB; COMP(b0, 0, 0);
                ISSUE(b0, a1 + 512); WAITV(8); SCHEDB; COMP(b1, 0, 8);
                ISSUE(b1, a1 + 768); WAITV(8); SCHEDB; COMP(b0, 0, 16);
                ISSUE(b0, a2);       WAITV(8); SCHEDB; COMP(b1, 0, 24);
                ISSUE(b1, a2 + 256); WAITV(8); SCHEDB; COMP(b0, 1, 0);
                ISSUE(b0, a2 + 512); WAITV(8); SCHEDB; COMP(b1, 1, 8);
                ISSUE(b1, a2 + 768); WAITV(8); SCHEDB; COMP(b0, 1, 16);
                                     WAITV(0); SCHEDB; COMP(b1, 1, 24);
            }
            // epilogue: tile0 = (i | f), tile1 = (g | o); pair-exchange via shfl_xor(8)
            {
                u16* hout = h1b + (size_t)(t & (RING - 1)) * SLOT;
                #pragma unroll
                for (int r = 0; r < 4; ++r) {
                    const float s0 = acc[0][0][r] + acc[0][1][r];
                    const float s1 = acc[1][0][r] + acc[1][1][r];
                    const float q0 = __shfl_xor(s0, 8);
                    const float q1 = __shfl_xor(s1, 8);
                    const float ip = (lo ? s0 : q0) + bii;
                    const float fp = (lo ? q0 : s0) + bif;
                    const float gp = (lo ? s1 : q1) + big;
                    const float op = (lo ? q1 : s1) + bio;
                    const float iv = 1.f / (1.f + expf(-ip));
                    const float fv = 1.f / (1.f + expf(-fp));
                    const float gv = tanhf(gp);
                    const float ov = 1.f / (1.f + expf(-op));
                    const float cv = fv * creg[r] + iv * gv;
                    creg[r] = cv;
                    if (lo) {
                        const int m = wave * 16 + kgi * 4 + r;
                        st_coh_u16(hout + (size_t)m * H_SZ + jj2, f2bf(ov * tanhf(cv)));
                    }
                }
                WAITV(0);
            }
            __syncthreads();
            if (tid == 0) st_flag(flagL1 + lb * FSTR, t + 1);
        }
        return;
    }

    // ======================= FC : blocks 192..195 =======================
    {
        const int fb = bid - 192, m0 = fb * 16;
        const u16* wp[2];
        #pragma unroll
        for (int nt = 0; nt < 2; ++nt)
            wp[nt] = Wfcc + (size_t)(wave * 32 + nt * 16 + l16) * H_SZ + kg8;

        for (int t = 0; t < S_LEN; ++t) {
            {
                const int* p = nullptr; int tgt = 0;
                if (tid < 128) { p = flagL1 + tid * FSTR; tgt = t + 1; }
                if (p && tgt > 0) while (ld_flag(p) < tgt) __builtin_amdgcn_s_sleep(2);
                __syncthreads();
            }
            if (t >= INVP && (t % INVP) == 0) l2_acquire_inv();

            const u16* aB = h1b + (size_t)(t & (RING - 1)) * SLOT
                          + (size_t)(m0 + l16) * H_SZ + kg8;
            f32x4 acc[2][2] = {};
            i32x4 buf[8];
            WAITV(0);
            #pragma unroll
            for (int c = 0; c < 4; ++c) {
                #pragma unroll
                for (int q = 0; q < 8; ++q) ld_g(buf[q], aB + c * 256 + q * 32);
                WAITV(0); SCHEDB;
                #pragma unroll
                for (int q = 0; q < 8; ++q) {
                    #pragma unroll
                    for (int nt = 0; nt < 2; ++nt)
                        acc[nt][q & 1] = mfma16(buf[q],
                            *(const u16x8*)(wp[nt] + (c * 8 + q) * 32), acc[nt][q & 1]);
                }
            }
            #pragma unroll
            for (int nt = 0; nt < 2; ++nt)
                #pragma unroll
                for (int r = 0; r < 4; ++r) {
                    const int m = kgi * 4 + r, n = wave * 32 + nt * 16 + l16;
                    sm.lg[m][n] = acc[nt][0][r] + acc[nt][1][r] + bfc[n];
                }
            __syncthreads();
            const int row = tid >> 4, sub = tid & 15;
            float vals[8]; float mx = -1e30f;
            #pragma unroll
            for (int q = 0; q < 8; ++q) { vals[q] = sm.lg[row][sub * 8 + q]; mx = fmaxf(mx, vals[q]); }
            #pragma unroll
            for (int o = 1; o < 16; o <<= 1) mx = fmaxf(mx, __shfl_xor(mx, o));
            float se = 0.f;
            #pragma unroll
            for (int q = 0; q < 8; ++q) se += expf(vals[q] - mx);
            #pragma unroll
            for (int o = 1; o < 16; o <<= 1) se += __shfl_xor(se, o);
            const float ls = mx + logf(se);
            float* op = out + (size_t)(m0 + row) * (S_LEN * V_SZ) + (size_t)t * V_SZ + sub * 8;
            #pragma unroll
            for (int q = 0; q < 8; ++q) op[q] = vals[q] - ls;

            __syncthreads();
            if (tid == 0) st_flag(flagFC + fb * FSTR, t + 1);
        }
    }
}

// =============================== launcher ==================================
extern "C" void kernel_launch(void* const* d_in, const int* in_sizes, int n_in,
                              void* d_out, int out_size, void* d_ws, size_t ws_size,
                              hipStream_t stream)
{
    const float* x    = (const float*)d_in[0];
    const float* Wih0 = (const float*)d_in[1];
    const float* Whh0 = (const float*)d_in[2];
    const float* bih0 = (const float*)d_in[3];
    const float* bhh0 = (const float*)d_in[4];
    const float* Wih1 = (const float*)d_in[5];
    const float* Whh1 = (const float*)d_in[6];
    const float* bih1 = (const float*)d_in[7];
    const float* bhh1 = (const float*)d_in[8];
    const float* Wfc  = (const float*)d_in[9];
    const float* bfc  = (const float*)d_in[10];
    float* out = (float*)d_out;

    u16* wih0 = (u16*)d_ws;                                  // 4096*128
    u16* whh0 = wih0 + (size_t)4096 * 128;                   // 4096*1024
    u16* wih1 = whh0 + (size_t)4096 * 1024;
    u16* whh1 = wih1 + (size_t)4096 * 1024;
    u16* wfc  = whh1 + (size_t)4096 * 1024;                  // 128*1024
    u16* h0b  = wfc  + (size_t)128 * 1024;                   // RING slots (padded)
    u16* h1b  = h0b + (size_t)RING * SLOT;
    int* flags  = (int*)(h1b + (size_t)RING * SLOT);         // 196*FSTR ints
    int* flagL0 = flags;
    int* flagL1 = flagL0 + 64 * FSTR;
    int* flagFC = flagL1 + 128 * FSTR;

    auto cvt = [&](const float* s, u16* d, int n) {
        cvt_kernel<<<(n / 4 + 255) / 256, 256, 0, stream>>>(s, d, n);
    };
    cvt(Wih0, wih0, 4096 * 128);
    cvt(Whh0, whh0, 4096 * 1024);
    cvt(Wih1, wih1, 4096 * 1024);
    cvt(Whh1, whh1, 4096 * 1024);
    cvt(Wfc,  wfc,  128 * 1024);
    // zero the t=-1 slots (slot RING-1 of each ring) + flags
    hipMemsetAsync(h0b + (size_t)(RING - 1) * SLOT, 0, (size_t)BH * sizeof(u16), stream);
    hipMemsetAsync(h1b + (size_t)(RING - 1) * SLOT, 0, (size_t)BH * sizeof(u16), stream);
    hipMemsetAsync(flags, 0, (size_t)196 * FSTR * sizeof(int), stream);

    persist_kernel<<<196, 256, 0, stream>>>(
        x, wih0, whh0, wih1, whh1, wfc,
        bih0, bhh0, bih1, bhh1, bfc,
        h0b, h1b, flagL0, flagL1, flagFC, out);
}

// Round 7
// 6385.448 us; speedup vs baseline: 1.0263x; 1.0263x over previous
//
#include <hip/hip_runtime.h>
#include <hip/hip_bf16.h>
#include <math.h>

// ---------------------------------------------------------------------------
// Round 7: persistent kernel. Changes vs round 5/6:
//  - Weight LDS: row-major (round-5 order) + T2 XOR swizzle ((row&7)<<4),
//    applied at BOTH staging-write and read (both-sides rule).
//  - h-stores coalesced: per-wave LDS mini-transpose -> 16B sc0sc1 stores
//    (8x fewer store messages than scattered 2B stores).
//  - 3-deep counted vmcnt load pipeline (24 outstanding, vmcnt(16)).
//  - x pre-converted to bf16 once; x loads issued BEFORE flag-wait.
//  - h loads plain cached (L2-shared) + RING=32 + agent acquire fence
//    every INVP=20 steps (stale-window 20 < reuse distance 32).
// Blocks: [0,64) L0 16-col, [64,192) L1 8-col, [192,196) FC. 256 thr.
// ---------------------------------------------------------------------------

#define S_LEN 512
#define B_SZ  64
#define V_SZ  128
#define H_SZ  1024
#define BH    65536
#define RING  32
#define SLOT  66560          // BH + 1024 u16 pad
#define FSTR  16
#define INVP  20

typedef unsigned short u16;
typedef unsigned short u16x8 __attribute__((ext_vector_type(8)));
typedef __bf16         bf16x8 __attribute__((ext_vector_type(8)));
typedef float          f32x4  __attribute__((ext_vector_type(4)));
typedef int            i32x4  __attribute__((ext_vector_type(4)));

__device__ __forceinline__ u16 f2bf(float f) {
    unsigned int u = __float_as_uint(f);
    u += 0x7fffu + ((u >> 16) & 1u);
    return (u16)(u >> 16);
}
__device__ __forceinline__ f32x4 mfma16(u16x8 a, u16x8 b, f32x4 c) {
    return __builtin_amdgcn_mfma_f32_16x16x32_bf16(
        __builtin_bit_cast(bf16x8, a), __builtin_bit_cast(bf16x8, b), c, 0, 0, 0);
}
__device__ __forceinline__ f32x4 mfma16(i32x4 a, u16x8 b, f32x4 c) {
    return __builtin_amdgcn_mfma_f32_16x16x32_bf16(
        __builtin_bit_cast(bf16x8, a), __builtin_bit_cast(bf16x8, b), c, 0, 0, 0);
}

__device__ __forceinline__ void ld_g(i32x4& d, const u16* p) {
    asm volatile("global_load_dwordx4 %0, %1, off" : "=v"(d) : "v"(p));
}
__device__ __forceinline__ void st_coh16(u16* p, u16x8 v) {
    i32x4 vv = __builtin_bit_cast(i32x4, v);
    asm volatile("global_store_dwordx4 %0, %1, off sc0 sc1" :: "v"(p), "v"(vv));
}
__device__ __forceinline__ int ld_flag(const int* p) {
    int v;
    asm volatile("global_load_dword %0, %1, off sc0 sc1\n\ts_waitcnt vmcnt(0)"
                 : "=v"(v) : "v"(p) : "memory");
    return v;
}
__device__ __forceinline__ void st_flag(int* p, int v) {
    asm volatile("global_store_dword %0, %1, off sc0 sc1" :: "v"(p), "v"(v));
}
#define WAITV(n) asm volatile("s_waitcnt vmcnt(" #n ")" ::: "memory")
#define LGKM0    asm volatile("s_waitcnt lgkmcnt(0)" ::: "memory")
#define SCHEDB   __builtin_amdgcn_sched_barrier(0)

__device__ __forceinline__ void l2_acquire_inv() {
    __builtin_amdgcn_fence(__ATOMIC_ACQUIRE, "agent");
}

__global__ __launch_bounds__(256) void cvt_kernel(const float* __restrict__ s,
                                                  u16* __restrict__ d, int n)
{
    int i = (blockIdx.x * 256 + threadIdx.x) * 4;
    if (i >= n) return;
    float4 v = *(const float4*)(s + i);
    ushort4 o;
    o.x = f2bf(v.x); o.y = f2bf(v.y); o.z = f2bf(v.z); o.w = f2bf(v.w);
    *(ushort4*)(d + i) = o;
}

union SMemL {
    struct { u16 whh[64 * 1024]; u16 wih[64 * 128]; u16 tr[4][384]; } l0;  // 150.5KB
    struct { u16 w[64 * 1024]; u16 tr[4][384]; } l1;                       // 131KB
    float lg[16][132];
};

__global__ __launch_bounds__(256, 1) void persist_kernel(
    const u16* __restrict__ xb,
    const u16* __restrict__ Wih0c, const u16* __restrict__ Whh0c,
    const u16* __restrict__ Wih1c, const u16* __restrict__ Whh1c,
    const u16* __restrict__ Wfcc,
    const float* __restrict__ bih0, const float* __restrict__ bhh0,
    const float* __restrict__ bih1, const float* __restrict__ bhh1,
    const float* __restrict__ bfc,
    u16* __restrict__ h0b, u16* __restrict__ h1b,
    int* __restrict__ flagL0, int* __restrict__ flagL1, int* __restrict__ flagFC,
    float* __restrict__ out)
{
    __shared__ SMemL sm;
    const int bid = blockIdx.x, tid = threadIdx.x;
    const int wave = tid >> 6, lane = tid & 63;
    const int l16 = lane & 15, kgi = lane >> 4, kg8 = kgi * 8;

    // ======================= LAYER 0 : blocks 0..63 =======================
    if (bid < 64) {
        const int j0 = bid * 16, jj = j0 + l16;
        for (int ch = tid; ch < 1024; ch += 256) {          // Wih0 [64][128]
            int row = ch >> 4, kc = ch & 15;
            int gr = (row >> 4) * H_SZ + j0 + (row & 15);
            int bo = (row * 256 + kc * 16) ^ ((row & 7) << 4);
            *(u16x8*)((char*)sm.l0.wih + bo) = *(const u16x8*)(Wih0c + (size_t)gr * V_SZ + kc * 8);
        }
        for (int ch = tid; ch < 8192; ch += 256) {          // Whh0 [64][1024]
            int row = ch >> 7, kc = ch & 127;
            int gr = (row >> 4) * H_SZ + j0 + (row & 15);
            int bo = (row * 2048 + kc * 16) ^ ((row & 7) << 4);
            *(u16x8*)((char*)sm.l0.whh + bo) = *(const u16x8*)(Whh0c + (size_t)gr * H_SZ + kc * 8);
        }
        __syncthreads();

        const float bii = bih0[jj]            + bhh0[jj];
        const float bif = bih0[H_SZ + jj]     + bhh0[H_SZ + jj];
        const float big = bih0[2 * H_SZ + jj] + bhh0[2 * H_SZ + jj];
        const float bio = bih0[3 * H_SZ + jj] + bhh0[3 * H_SZ + jj];

        const int swz = (l16 & 7) << 4;
        int whh_rb[4], wih_rb[4];
        #pragma unroll
        for (int g = 0; g < 4; ++g) {
            whh_rb[g] = (g * 16 + l16) * 2048 + kgi * 16;
            wih_rb[g] = (g * 16 + l16) * 256 + kgi * 16;
        }
        const int arow = wave * 16 + l16;
        const u16* xrow = xb + (size_t)arow * (S_LEN * V_SZ);
        u16* trw = sm.l0.tr[wave];
        float creg[4] = {0.f, 0.f, 0.f, 0.f};

        for (int t = 0; t < S_LEN; ++t) {
            // x prefetch (no dependency on flags)
            i32x4 xq[4];
            {
                const u16* xp = xrow + (size_t)t * V_SZ + kg8;
                #pragma unroll
                for (int i = 0; i < 4; ++i) ld_g(xq[i], xp + i * 32);
            }
            // waits: h0[t-1] complete; WAR: L1 consumed slot t-RING
            {
                const int* p = nullptr; int tgt = 0;
                if (tid < 64)                      { p = flagL0 + tid * FSTR;        tgt = t; }
                else if (tid < 192 && t >= RING)   { p = flagL1 + (tid - 64) * FSTR; tgt = t - (RING - 1); }
                if (p && tgt > 0) while (ld_flag(p) < tgt) __builtin_amdgcn_s_sleep(2);
                __syncthreads();
            }
            if (t >= INVP && (t % INVP) == 0) l2_acquire_inv();
            WAITV(0); SCHEDB;                                  // xq valid for all

            f32x4 acc[4][2] = {};
            auto ISSUE = [&](i32x4 (&buf)[8], const u16* base) {
                #pragma unroll
                for (int q = 0; q < 8; ++q) ld_g(buf[q], base + q * 32);
            };
            auto COMP = [&](i32x4 (&buf)[8], int k0) {
                #pragma unroll
                for (int q = 0; q < 8; ++q)
                    #pragma unroll
                    for (int g = 0; g < 4; ++g)
                        acc[g][q & 1] = mfma16(buf[q],
                            *(const u16x8*)((char*)sm.l0.whh + ((whh_rb[g] + (k0 + q) * 64) ^ swz)),
                            acc[g][q & 1]);
            };
            const u16* aB = h0b + (size_t)((t - 1) & (RING - 1)) * SLOT
                          + (size_t)arow * H_SZ + kg8;
            i32x4 b0[8], b1[8], b2[8];
            ISSUE(b0, aB); ISSUE(b1, aB + 256); ISSUE(b2, aB + 512);
            SCHEDB;
            // x pass (regs already loaded)
            #pragma unroll
            for (int i = 0; i < 4; ++i)
                #pragma unroll
                for (int g = 0; g < 4; ++g)
                    acc[g][i & 1] = mfma16(xq[i],
                        *(const u16x8*)((char*)sm.l0.wih + ((wih_rb[g] + i * 64) ^ swz)),
                        acc[g][i & 1]);
            WAITV(16); SCHEDB; COMP(b0, 0);  ISSUE(b0, aB + 768);
            WAITV(16); SCHEDB; COMP(b1, 8);
            WAITV(8);  SCHEDB; COMP(b2, 16);
            WAITV(0);  SCHEDB; COMP(b0, 24);

            // fused LSTM update -> LDS mini-transpose -> 16B coherent stores
            {
                u16* hout = h0b + (size_t)(t & (RING - 1)) * SLOT;
                #pragma unroll
                for (int r = 0; r < 4; ++r) {
                    const float ip = acc[0][0][r] + acc[0][1][r] + bii;
                    const float fp = acc[1][0][r] + acc[1][1][r] + bif;
                    const float gp = acc[2][0][r] + acc[2][1][r] + big;
                    const float op = acc[3][0][r] + acc[3][1][r] + bio;
                    const float iv = 1.f / (1.f + expf(-ip));
                    const float fv = 1.f / (1.f + expf(-fp));
                    const float gv = tanhf(gp);
                    const float ov = 1.f / (1.f + expf(-op));
                    const float cv = fv * creg[r] + iv * gv;
                    creg[r] = cv;
                    trw[(kgi * 4 + r) * 24 + l16] = f2bf(ov * tanhf(cv));
                }
                LGKM0; SCHEDB;
                if (lane < 32) {
                    int m = lane >> 1, jb = lane & 1;
                    u16x8 v = *(const u16x8*)&trw[m * 24 + jb * 8];
                    st_coh16(hout + (size_t)(wave * 16 + m) * H_SZ + j0 + jb * 8, v);
                }
                WAITV(0);
            }
            __syncthreads();
            if (tid == 0) st_flag(flagL0 + bid * FSTR, t + 1);
        }
        return;
    }

    // ======================= LAYER 1 : blocks 64..191 =======================
    if (bid < 192) {
        const int lb = bid - 64, j0 = lb * 8, jj2 = j0 + (l16 & 7);
        for (int ch = tid; ch < 8192; ch += 256) {          // [64][1024]: 2 regions
            int ldsrow = ch >> 7, kc = ch & 127;
            int region = ldsrow >> 5, rl = ldsrow & 31;
            int gr = (rl >> 3) * H_SZ + j0 + (rl & 7);
            const u16* src = (region ? Whh1c : Wih1c) + (size_t)gr * H_SZ + kc * 8;
            int bo = (ldsrow * 2048 + kc * 16) ^ ((ldsrow & 7) << 4);
            *(u16x8*)((char*)sm.l1.w + bo) = *(const u16x8*)src;
        }
        __syncthreads();

        const float bii = bih1[jj2]            + bhh1[jj2];
        const float bif = bih1[H_SZ + jj2]     + bhh1[H_SZ + jj2];
        const float big = bih1[2 * H_SZ + jj2] + bhh1[2 * H_SZ + jj2];
        const float bio = bih1[3 * H_SZ + jj2] + bhh1[3 * H_SZ + jj2];
        const bool lo = (l16 < 8);

        const int swz = (l16 & 7) << 4;
        int wrb[2][2];
        #pragma unroll
        for (int region = 0; region < 2; ++region)
            #pragma unroll
            for (int nt = 0; nt < 2; ++nt)
                wrb[region][nt] = (region * 32 + nt * 16 + l16) * 2048 + kgi * 16;
        const int arow = wave * 16 + l16;
        u16* trw = sm.l1.tr[wave];
        float creg[4] = {0.f, 0.f, 0.f, 0.f};

        for (int t = 0; t < S_LEN; ++t) {
            {
                const int* p = nullptr; int tgt = 0;
                if (tid < 64)                        { p = flagL0 + tid * FSTR;         tgt = t + 1; }
                else if (tid < 192)                  { p = flagL1 + (tid - 64) * FSTR;  tgt = t; }
                else if (tid < 196 && t >= RING)     { p = flagFC + (tid - 192) * FSTR; tgt = t - (RING - 1); }
                if (p && tgt > 0) while (ld_flag(p) < tgt) __builtin_amdgcn_s_sleep(2);
                __syncthreads();
            }
            if (t >= INVP && (t % INVP) == 0) l2_acquire_inv();

            f32x4 acc[2][2] = {};
            auto ISSUE = [&](i32x4 (&buf)[8], const u16* base) {
                #pragma unroll
                for (int q = 0; q < 8; ++q) ld_g(buf[q], base + q * 32);
            };
            auto COMP = [&](i32x4 (&buf)[8], int region, int k0) {
                #pragma unroll
                for (int q = 0; q < 8; ++q)
                    #pragma unroll
                    for (int nt = 0; nt < 2; ++nt)
                        acc[nt][q & 1] = mfma16(buf[q],
                            *(const u16x8*)((char*)sm.l1.w + ((wrb[region][nt] + (k0 + q) * 64) ^ swz)),
                            acc[nt][q & 1]);
            };
            const u16* a1 = h0b + (size_t)(t & (RING - 1)) * SLOT + (size_t)arow * H_SZ + kg8;
            const u16* a2 = h1b + (size_t)((t - 1) & (RING - 1)) * SLOT + (size_t)arow * H_SZ + kg8;
            i32x4 b0[8], b1[8], b2[8];
            ISSUE(b0, a1); ISSUE(b1, a1 + 256); ISSUE(b2, a1 + 512);
            SCHEDB;
            WAITV(16); SCHEDB; COMP(b0, 0, 0);  ISSUE(b0, a1 + 768);
            WAITV(16); SCHEDB; COMP(b1, 0, 8);  ISSUE(b1, a2);
            WAITV(16); SCHEDB; COMP(b2, 0, 16); ISSUE(b2, a2 + 256);
            WAITV(16); SCHEDB; COMP(b0, 0, 24); ISSUE(b0, a2 + 512);
            WAITV(16); SCHEDB; COMP(b1, 1, 0);  ISSUE(b1, a2 + 768);
            WAITV(16); SCHEDB; COMP(b2, 1, 8);
            WAITV(8);  SCHEDB; COMP(b0, 1, 16);
            WAITV(0);  SCHEDB; COMP(b1, 1, 24);

            // epilogue: tile0=(i|f), tile1=(g|o); pair exchange; transpose-store
            {
                #pragma unroll
                for (int r = 0; r < 4; ++r) {
                    const float s0 = acc[0][0][r] + acc[0][1][r];
                    const float s1 = acc[1][0][r] + acc[1][1][r];
                    const float q0 = __shfl_xor(s0, 8);
                    const float q1 = __shfl_xor(s1, 8);
                    const float ip = (lo ? s0 : q0) + bii;
                    const float fp = (lo ? q0 : s0) + bif;
                    const float gp = (lo ? s1 : q1) + big;
                    const float op = (lo ? q1 : s1) + bio;
                    const float iv = 1.f / (1.f + expf(-ip));
                    const float fv = 1.f / (1.f + expf(-fp));
                    const float gv = tanhf(gp);
                    const float ov = 1.f / (1.f + expf(-op));
                    const float cv = fv * creg[r] + iv * gv;
                    creg[r] = cv;
                    if (lo) trw[(kgi * 4 + r) * 24 + (l16 & 7)] = f2bf(ov * tanhf(cv));
                }
                LGKM0; SCHEDB;
                if (lane < 16) {
                    int m = lane;
                    u16x8 v = *(const u16x8*)&trw[m * 24];
                    st_coh16(h1b + (size_t)(t & (RING - 1)) * SLOT
                             + (size_t)(wave * 16 + m) * H_SZ + j0, v);
                }
                WAITV(0);
            }
            __syncthreads();
            if (tid == 0) st_flag(flagL1 + lb * FSTR, t + 1);
        }
        return;
    }

    // ======================= FC : blocks 192..195 =======================
    {
        const int fb = bid - 192, m0 = fb * 16;
        const u16* wp[2];
        #pragma unroll
        for (int nt = 0; nt < 2; ++nt)
            wp[nt] = Wfcc + (size_t)(wave * 32 + nt * 16 + l16) * H_SZ + kg8;

        for (int t = 0; t < S_LEN; ++t) {
            {
                const int* p = nullptr; int tgt = 0;
                if (tid < 128) { p = flagL1 + tid * FSTR; tgt = t + 1; }
                if (p && tgt > 0) while (ld_flag(p) < tgt) __builtin_amdgcn_s_sleep(2);
                __syncthreads();
            }
            if (t >= INVP && (t % INVP) == 0) l2_acquire_inv();

            const u16* aB = h1b + (size_t)(t & (RING - 1)) * SLOT
                          + (size_t)(m0 + l16) * H_SZ + kg8;
            f32x4 acc[2][2] = {};
            i32x4 buf[8];
            WAITV(0);
            #pragma unroll
            for (int c = 0; c < 4; ++c) {
                #pragma unroll
                for (int q = 0; q < 8; ++q) ld_g(buf[q], aB + c * 256 + q * 32);
                WAITV(0); SCHEDB;
                #pragma unroll
                for (int q = 0; q < 8; ++q) {
                    #pragma unroll
                    for (int nt = 0; nt < 2; ++nt)
                        acc[nt][q & 1] = mfma16(buf[q],
                            *(const u16x8*)(wp[nt] + (c * 8 + q) * 32), acc[nt][q & 1]);
                }
            }
            #pragma unroll
            for (int nt = 0; nt < 2; ++nt)
                #pragma unroll
                for (int r = 0; r < 4; ++r) {
                    const int m = kgi * 4 + r, n = wave * 32 + nt * 16 + l16;
                    sm.lg[m][n] = acc[nt][0][r] + acc[nt][1][r] + bfc[n];
                }
            __syncthreads();
            const int row = tid >> 4, sub = tid & 15;
            float vals[8]; float mx = -1e30f;
            #pragma unroll
            for (int q = 0; q < 8; ++q) { vals[q] = sm.lg[row][sub * 8 + q]; mx = fmaxf(mx, vals[q]); }
            #pragma unroll
            for (int o = 1; o < 16; o <<= 1) mx = fmaxf(mx, __shfl_xor(mx, o));
            float se = 0.f;
            #pragma unroll
            for (int q = 0; q < 8; ++q) se += expf(vals[q] - mx);
            #pragma unroll
            for (int o = 1; o < 16; o <<= 1) se += __shfl_xor(se, o);
            const float ls = mx + logf(se);
            float* op = out + (size_t)(m0 + row) * (S_LEN * V_SZ) + (size_t)t * V_SZ + sub * 8;
            #pragma unroll
            for (int q = 0; q < 8; ++q) op[q] = vals[q] - ls;

            __syncthreads();
            if (tid == 0) st_flag(flagFC + fb * FSTR, t + 1);
        }
    }
}

// =============================== launcher ==================================
extern "C" void kernel_launch(void* const* d_in, const int* in_sizes, int n_in,
                              void* d_out, int out_size, void* d_ws, size_t ws_size,
                              hipStream_t stream)
{
    const float* x    = (const float*)d_in[0];
    const float* Wih0 = (const float*)d_in[1];
    const float* Whh0 = (const float*)d_in[2];
    const float* bih0 = (const float*)d_in[3];
    const float* bhh0 = (const float*)d_in[4];
    const float* Wih1 = (const float*)d_in[5];
    const float* Whh1 = (const float*)d_in[6];
    const float* bih1 = (const float*)d_in[7];
    const float* bhh1 = (const float*)d_in[8];
    const float* Wfc  = (const float*)d_in[9];
    const float* bfc  = (const float*)d_in[10];
    float* out = (float*)d_out;

    u16* wih0 = (u16*)d_ws;                                  // 4096*128
    u16* whh0 = wih0 + (size_t)4096 * 128;                   // 4096*1024
    u16* wih1 = whh0 + (size_t)4096 * 1024;
    u16* whh1 = wih1 + (size_t)4096 * 1024;
    u16* wfc  = whh1 + (size_t)4096 * 1024;                  // 128*1024
    u16* xbuf = wfc  + (size_t)128 * 1024;                   // 64*512*128 bf16
    u16* h0b  = xbuf + (size_t)B_SZ * S_LEN * V_SZ;
    u16* h1b  = h0b + (size_t)RING * SLOT;
    int* flags  = (int*)(h1b + (size_t)RING * SLOT);         // 196*FSTR ints
    int* flagL0 = flags;
    int* flagL1 = flagL0 + 64 * FSTR;
    int* flagFC = flagL1 + 128 * FSTR;
    // total ws ~= 43.5 MB (same footprint class as passing rounds 5/6)

    auto cvt = [&](const float* s, u16* d, int n) {
        cvt_kernel<<<(n / 4 + 255) / 256, 256, 0, stream>>>(s, d, n);
    };
    cvt(Wih0, wih0, 4096 * 128);
    cvt(Whh0, whh0, 4096 * 1024);
    cvt(Wih1, wih1, 4096 * 1024);
    cvt(Whh1, whh1, 4096 * 1024);
    cvt(Wfc,  wfc,  128 * 1024);
    cvt(x,    xbuf, B_SZ * S_LEN * V_SZ);
    hipMemsetAsync(h0b + (size_t)(RING - 1) * SLOT, 0, (size_t)BH * sizeof(u16), stream);
    hipMemsetAsync(h1b + (size_t)(RING - 1) * SLOT, 0, (size_t)BH * sizeof(u16), stream);
    hipMemsetAsync(flags, 0, (size_t)196 * FSTR * sizeof(int), stream);

    persist_kernel<<<196, 256, 0, stream>>>(
        xbuf, wih0, whh0, wih1, whh1, wfc,
        bih0, bhh0, bih1, bhh1, bfc,
        h0b, h1b, flagL0, flagL1, flagFC, out);
}